// Round 4
// baseline (235.251 us; speedup 1.0000x reference)
//
#include <hip/hip_runtime.h>

// Shapes (fixed): B=4, N=256, D_MODEL=256, D_EDGE=64, H=8, C=32
// workspace layout (float offsets)
#define OQ  0
#define OK  262144   // KT[b][hc][j]  (K stored TRANSPOSED)
#define OV  524288
#define OS  786432   // skip = x@W_s + b_s
#define OWT 1048576  // WeT[hc][d] = W_e[d][hc]
// total ws need: 1064960 floats = 4.06 MB

static __device__ __forceinline__ float4 ld4(const float* p) {
    return *reinterpret_cast<const float4*>(p);
}

// ---------------------------------------------------------------------------
// Kernel 1: Q/KT/V/skip projections. grid = 1025 x 256.
// bid<1024: mat = bid>>8 (0=Q,1=K->KT,2=V,3=S); sub = bid&255:
//   rowtile = sub>>2 (16 rows), coltile = sub&3 (64 cols). 4 outputs/thread.
// bid==1024: W_e transpose.
// ---------------------------------------------------------------------------
__global__ __launch_bounds__(256) void fused_qkvs(
    const float* __restrict__ x,
    const float* __restrict__ Wq, const float* __restrict__ bq,
    const float* __restrict__ Wk, const float* __restrict__ bk,
    const float* __restrict__ Wv, const float* __restrict__ bv,
    const float* __restrict__ Wsk, const float* __restrict__ bsk,
    const float* __restrict__ We, float* __restrict__ ws)
{
    const int t = threadIdx.x;
    const int bid = blockIdx.x;

    if (bid == 1024) {   // W_e (64x256) -> WeT[hc*64+d]
        #pragma unroll
        for (int k = 0; k < 64; ++k) {
            int o = k * 256 + t;
            ws[OWT + o] = We[(o & 63) * 256 + (o >> 6)];
        }
        return;
    }

    __shared__ float xs[16 * 256];   // x tile
    __shared__ float xp[64 * 17];    // KT transpose bounce (padded)

    const int mat = bid >> 8;
    const int sub = bid & 255;
    const int r0 = (sub >> 2) * 16;  // global row base (tiles never straddle batch)
    const int c0 = (sub & 3) * 64;   // col base
    const float* W; const float* bb;
    if      (mat == 0) { W = Wq;  bb = bq;  }
    else if (mat == 1) { W = Wk;  bb = bk;  }
    else if (mat == 2) { W = Wv;  bb = bv;  }
    else               { W = Wsk; bb = bsk; }

    {   // stage x tile (coalesced float4)
        const float4* xsrc = reinterpret_cast<const float4*>(x + r0 * 256);
        float4* xd = reinterpret_cast<float4*>(xs);
        #pragma unroll
        for (int k = 0; k < 4; ++k) xd[t + k * 256] = xsrc[t + k * 256];
    }
    __syncthreads();

    const int tr = t >> 4;   // row 0..15
    const int tc = t & 15;   // col group 0..15 (x4 floats)
    float a0 = 0.f, a1 = 0.f, a2 = 0.f, a3 = 0.f;
    #pragma unroll 8
    for (int d = 0; d < 256; ++d) {
        float4 wv = ld4(&W[d * 256 + c0 + tc * 4]);   // 256B/wave, L2-hot
        float xv = xs[tr * 256 + d];                  // broadcast
        a0 += xv * wv.x; a1 += xv * wv.y; a2 += xv * wv.z; a3 += xv * wv.w;
    }
    float4 bv4 = ld4(&bb[c0 + tc * 4]);
    a0 += bv4.x; a1 += bv4.y; a2 += bv4.z; a3 += bv4.w;

    if (mat != 1) {
        float* outp = ws + (mat == 0 ? OQ : (mat == 2 ? OV : OS));
        float4 o = make_float4(a0, a1, a2, a3);
        *reinterpret_cast<float4*>(&outp[(r0 + tr) * 256 + c0 + tc * 4]) = o;
    } else {
        // K stored transposed: KT[b][hc][rb]. LDS bounce for coalesced stores.
        xp[(tc * 4 + 0) * 17 + tr] = a0;
        xp[(tc * 4 + 1) * 17 + tr] = a1;
        xp[(tc * 4 + 2) * 17 + tr] = a2;
        xp[(tc * 4 + 3) * 17 + tr] = a3;
        __syncthreads();
        const int b = r0 >> 8, rb0 = r0 & 255;
        float* KT = ws + OK + b * 65536;
        const int rl = t & 15;
        #pragma unroll
        for (int q2 = 0; q2 < 4; ++q2) {
            int hcl = q2 * 16 + (t >> 4);
            KT[(c0 + hcl) * 256 + rb0 + rl] = xp[hcl * 17 + rl];
        }
    }
}

// ---------------------------------------------------------------------------
// Kernel 2: fused edge-biased attention. One block per (b,i) row.
// scores = (Q_i.K_j + edge_ij.P_i)*scale ; softmax over j ; out = alpha.(V+E)+skip
// E never materialized (P-trick / A-trick). K read via KT (coalesced).
// QE pass reads edge via XOR-swizzled LDS chunks (64 j x 64 d).
// ---------------------------------------------------------------------------
__global__ __launch_bounds__(256) void fused_attn(
    const float* __restrict__ edge, const unsigned char* __restrict__ mask,
    const float* __restrict__ We, const float* __restrict__ ws,
    float* __restrict__ out)
{
    __shared__ float qs[256];       // Q row
    __shared__ float Ps[512];       // P[h][d]
    __shared__ float es[64 * 64];   // swizzled edge chunk (16 KB)
    __shared__ float pt[8 * 260];   // scores then p, [h][j]
    __shared__ float As[512];       // A[h][d]
    __shared__ float mx[8];
    __shared__ float sm[8];
    __shared__ int mflag;           // 1 = byte mask, 0 = int32 mask

    const float* Q  = ws + OQ;
    const float* KT = ws + OK;
    const float* V  = ws + OV;
    const float* SK = ws + OS;
    const float* WT = ws + OWT;

    const int t   = threadIdx.x;
    const int row = blockIdx.x;     // b*256 + i
    const int b   = row >> 8;
    const float* erow = edge + (size_t)row * (256 * 64);

    if (t == 0) mflag = 0;
    __syncthreads();
    {   // mask layout detect: int32 0/1 has zero bytes at off%4!=0
        int found = 0;
        #pragma unroll
        for (int k = 0; k < 16; ++k)
            if ((k & 3) != 0 && mask[t * 16 + k]) found = 1;
        if (found) mflag = 1;       // benign same-value race
    }
    qs[t] = Q[row * 256 + t];
    __syncthreads();
    const int MB = mflag;

    // P[h][d] = sum_c q[h*32+c] * WeT[(h*32+c)*64+d]  (coalesced, L2-hot)
    #pragma unroll
    for (int rep = 0; rep < 2; ++rep) {
        int idx = t + rep * 256;
        int h = idx >> 6, d = idx & 63;
        float pa = 0.f, pb = 0.f;
        #pragma unroll
        for (int c = 0; c < 32; c += 2) {
            pa += qs[h * 32 + c]     * WT[(h * 32 + c) * 64 + d];
            pb += qs[h * 32 + c + 1] * WT[(h * 32 + c + 1) * 64 + d];
        }
        Ps[idx] = pa + pb;
    }
    __syncthreads();

    // ---- scores in 4 chunks of 64 j; thread = (j_local, head-pair) ----
    const int jl = t & 63;
    const int hp = t >> 6;
    const int h0 = 2 * hp, h1 = 2 * hp + 1;
    const float scale = 0.17677669529663687f;   // 1/sqrt(32)

    for (int c4 = 0; c4 < 4; ++c4) {
        {   // stage 64x64 chunk = 4096 floats = 1024 float4; XOR swizzle (T2)
            const float4* src = reinterpret_cast<const float4*>(erow + c4 * 4096);
            #pragma unroll
            for (int m = 0; m < 4; ++m) {
                int q = m * 256 + t;          // float4 index 0..1023
                int r = q >> 4, k = q & 15;   // row 0..63, col-group 0..15
                *reinterpret_cast<float4*>(&es[r * 64 + ((k ^ (r & 15)) * 4)]) = src[q];
            }
        }
        __syncthreads();

        const int j = c4 * 64 + jl;
        // QE: edge row j . P[h]  (LDS, bank-spread via swizzle)
        float sa0 = 0.f, sb0 = 0.f, sa1 = 0.f, sb1 = 0.f;
        #pragma unroll
        for (int k = 0; k < 16; ++k) {
            float4 ev = ld4(&es[jl * 64 + ((k ^ (jl & 15)) * 4)]);
            float4 p0 = ld4(&Ps[h0 * 64 + k * 4]);   // broadcast
            float4 p1 = ld4(&Ps[h1 * 64 + k * 4]);
            sa0 += ev.x * p0.x + ev.y * p0.y; sb0 += ev.z * p0.z + ev.w * p0.w;
            sa1 += ev.x * p1.x + ev.y * p1.y; sb1 += ev.z * p1.z + ev.w * p1.w;
        }
        // QK: coalesced KT columns (lane j contiguous)
        const float* kt = KT + b * 65536 + j;
        #pragma unroll 8
        for (int c = 0; c < 32; ++c) {
            sa0 += qs[h0 * 32 + c] * kt[(h0 * 32 + c) * 256];
            sa1 += qs[h1 * 32 + c] * kt[(h1 * 32 + c) * 256];
        }
        float s0 = (sa0 + sb0) * scale;
        float s1 = (sa1 + sb1) * scale;
        bool mk = MB ? (mask[row * 256 + j] != 0)
                     : (reinterpret_cast<const int*>(mask)[row * 256 + j] != 0);
        if (!mk) { s0 = -1e30f; s1 = -1e30f; }
        pt[h0 * 260 + j] = s0;
        pt[h1 * 260 + j] = s1;
        __syncthreads();   // es reused next chunk
    }

    // ---- per-head max over j ----
    {
        int h = t >> 5, l = t & 31;
        float m = -1e30f;
        #pragma unroll
        for (int k = 0; k < 8; ++k) m = fmaxf(m, pt[h * 260 + l + k * 32]);
        #pragma unroll
        for (int off = 16; off; off >>= 1) m = fmaxf(m, __shfl_xor(m, off));
        if (l == 0) mx[h] = m;
    }
    __syncthreads();

    // ---- p = exp(s - max), masked lanes exactly 0 ----
    {
        bool mkt = MB ? (mask[row * 256 + t] != 0)
                      : (reinterpret_cast<const int*>(mask)[row * 256 + t] != 0);
        #pragma unroll
        for (int h = 0; h < 8; ++h) {
            float s = pt[h * 260 + t];
            pt[h * 260 + t] = mkt ? __expf(s - mx[h]) : 0.f;
        }
    }
    __syncthreads();

    // ---- per-head sum over j ----
    {
        int h = t >> 5, l = t & 31;
        float a = 0.f;
        #pragma unroll
        for (int k = 0; k < 8; ++k) a += pt[h * 260 + l + k * 32];
        #pragma unroll
        for (int off = 16; off; off >>= 1) a += __shfl_xor(a, off);
        if (l == 0) sm[h] = a;      // sum==0 => fully masked row
    }
    __syncthreads();

    // ---- out_V[h,c]: thread t = h*32+c; 4-acc ILP ----
    float accV;
    {
        int h = t >> 5;
        const float* vcol = V + (b << 8) * 256 + t;
        float v0 = 0.f, v1 = 0.f, v2 = 0.f, v3 = 0.f;
        #pragma unroll 4
        for (int j4 = 0; j4 < 64; ++j4) {
            float4 pv = ld4(&pt[h * 260 + j4 * 4]);     // broadcast
            v0 += pv.x * vcol[(j4 * 4 + 0) * 256];      // coalesced over t
            v1 += pv.y * vcol[(j4 * 4 + 1) * 256];
            v2 += pv.z * vcol[(j4 * 4 + 2) * 256];
            v3 += pv.w * vcol[(j4 * 4 + 3) * 256];
        }
        accV = (v0 + v1) + (v2 + v3);
    }

    // ---- A[h][d] = sum_j p[j,h]*edge[j,d]; coalesced edge (L2-hot), 8-acc ----
    {
        int h2 = t >> 6, d = t & 63;
        float a00=0.f,a01=0.f,a02=0.f,a03=0.f,a10=0.f,a11=0.f,a12=0.f,a13=0.f;
        #pragma unroll 4
        for (int j4 = 0; j4 < 64; ++j4) {
            float4 p0 = ld4(&pt[h2 * 260 + j4 * 4]);
            float4 p1 = ld4(&pt[(h2 + 4) * 260 + j4 * 4]);
            float e0 = erow[(j4 * 4 + 0) * 64 + d];
            float e1 = erow[(j4 * 4 + 1) * 64 + d];
            float e2 = erow[(j4 * 4 + 2) * 64 + d];
            float e3 = erow[(j4 * 4 + 3) * 64 + d];
            a00 += p0.x * e0; a01 += p0.y * e1; a02 += p0.z * e2; a03 += p0.w * e3;
            a10 += p1.x * e0; a11 += p1.y * e1; a12 += p1.z * e2; a13 += p1.w * e3;
        }
        As[h2 * 64 + d]       = (a00 + a01) + (a02 + a03);
        As[(h2 + 4) * 64 + d] = (a10 + a11) + (a12 + a13);
    }
    __syncthreads();

    // ---- out_E[h,c] = sum_d A[h,d]*W_e[d,hc]; normalize + skip ----
    {
        int h = t >> 5;
        float e0 = 0.f, e1 = 0.f, e2 = 0.f, e3 = 0.f;
        #pragma unroll
        for (int d4 = 0; d4 < 16; ++d4) {
            float4 av = ld4(&As[h * 64 + d4 * 4]);      // broadcast
            e0 += av.x * We[(d4 * 4 + 0) * 256 + t];    // coalesced
            e1 += av.y * We[(d4 * 4 + 1) * 256 + t];
            e2 += av.z * We[(d4 * 4 + 2) * 256 + t];
            e3 += av.w * We[(d4 * 4 + 3) * 256 + t];
        }
        float accE = (e0 + e1) + (e2 + e3);
        float denom = sm[h];
        float inv = denom > 0.f ? 1.f / denom : 0.f;    // nan_to_num
        out[row * 256 + t] = (accV + accE) * inv + SK[row * 256 + t];
    }
}

// ---------------------------------------------------------------------------
extern "C" void kernel_launch(void* const* d_in, const int* in_sizes, int n_in,
                              void* d_out, int out_size, void* d_ws, size_t ws_size,
                              hipStream_t stream) {
    const float* x    = (const float*)d_in[0];
    const float* edge = (const float*)d_in[1];
    const unsigned char* mask = (const unsigned char*)d_in[2];  // layout auto-detected
    const float* Wq = (const float*)d_in[3];
    const float* bq = (const float*)d_in[4];
    const float* Wk = (const float*)d_in[5];
    const float* bk = (const float*)d_in[6];
    const float* Wv = (const float*)d_in[7];
    const float* bv = (const float*)d_in[8];
    const float* We = (const float*)d_in[9];
    const float* Wsk = (const float*)d_in[10];
    const float* bsk = (const float*)d_in[11];
    float* out = (float*)d_out;
    float* ws  = (float*)d_ws;

    fused_qkvs<<<1025, 256, 0, stream>>>(x, Wq, bq, Wk, bk, Wv, bv, Wsk, bsk, We, ws);
    fused_attn<<<1024, 256, 0, stream>>>(edge, mask, We, ws, out);
}

// Round 7
// 221.821 us; speedup vs baseline: 1.0605x; 1.0605x over previous
//
#include <hip/hip_runtime.h>

// Shapes (fixed): B=4, N=256, D_MODEL=256, D_EDGE=64, H=8, C=32
// workspace layout (float offsets)
#define OQ  0
#define OK  262144   // KT[b][hc][j]  (K stored TRANSPOSED)
#define OV  524288
#define OS  786432   // skip = x@W_s + b_s
#define OWT 1048576  // WeT[hc][d] = W_e[d][hc]

static __device__ __forceinline__ float4 ld4(const float* p) {
    return *reinterpret_cast<const float4*>(p);
}

// ---------------------------------------------------------------------------
// Kernel 1: Q/KT/V/skip projections (unchanged — verified passing in round 4).
// ---------------------------------------------------------------------------
__global__ __launch_bounds__(256) void fused_qkvs(
    const float* __restrict__ x,
    const float* __restrict__ Wq, const float* __restrict__ bq,
    const float* __restrict__ Wk, const float* __restrict__ bk,
    const float* __restrict__ Wv, const float* __restrict__ bv,
    const float* __restrict__ Wsk, const float* __restrict__ bsk,
    const float* __restrict__ We, float* __restrict__ ws)
{
    const int t = threadIdx.x;
    const int bid = blockIdx.x;

    if (bid == 1024) {   // W_e (64x256) -> WeT[hc*64+d]
        #pragma unroll
        for (int k = 0; k < 64; ++k) {
            int o = k * 256 + t;
            ws[OWT + o] = We[(o & 63) * 256 + (o >> 6)];
        }
        return;
    }

    __shared__ float xs[16 * 256];
    __shared__ float xp[64 * 17];

    const int mat = bid >> 8;
    const int sub = bid & 255;
    const int r0 = (sub >> 2) * 16;
    const int c0 = (sub & 3) * 64;
    const float* W; const float* bb;
    if      (mat == 0) { W = Wq;  bb = bq;  }
    else if (mat == 1) { W = Wk;  bb = bk;  }
    else if (mat == 2) { W = Wv;  bb = bv;  }
    else               { W = Wsk; bb = bsk; }

    {
        const float4* xsrc = reinterpret_cast<const float4*>(x + r0 * 256);
        float4* xd = reinterpret_cast<float4*>(xs);
        #pragma unroll
        for (int k = 0; k < 4; ++k) xd[t + k * 256] = xsrc[t + k * 256];
    }
    __syncthreads();

    const int tr = t >> 4;
    const int tc = t & 15;
    float a0 = 0.f, a1 = 0.f, a2 = 0.f, a3 = 0.f;
    #pragma unroll 8
    for (int d = 0; d < 256; ++d) {
        float4 wv = ld4(&W[d * 256 + c0 + tc * 4]);
        float xv = xs[tr * 256 + d];
        a0 += xv * wv.x; a1 += xv * wv.y; a2 += xv * wv.z; a3 += xv * wv.w;
    }
    float4 bv4 = ld4(&bb[c0 + tc * 4]);
    a0 += bv4.x; a1 += bv4.y; a2 += bv4.z; a3 += bv4.w;

    if (mat != 1) {
        float* outp = ws + (mat == 0 ? OQ : (mat == 2 ? OV : OS));
        float4 o = make_float4(a0, a1, a2, a3);
        *reinterpret_cast<float4*>(&outp[(r0 + tr) * 256 + c0 + tc * 4]) = o;
    } else {
        xp[(tc * 4 + 0) * 17 + tr] = a0;
        xp[(tc * 4 + 1) * 17 + tr] = a1;
        xp[(tc * 4 + 2) * 17 + tr] = a2;
        xp[(tc * 4 + 3) * 17 + tr] = a3;
        __syncthreads();
        const int b = r0 >> 8, rb0 = r0 & 255;
        float* KT = ws + OK + b * 65536;
        const int rl = t & 15;
        #pragma unroll
        for (int q2 = 0; q2 < 4; ++q2) {
            int hcl = q2 * 16 + (t >> 4);
            KT[(c0 + hcl) * 256 + rb0 + rl] = xp[hcl * 17 + rl];
        }
    }
}

// ---------------------------------------------------------------------------
// Kernel 2: FLASH-STYLE fused edge attention. One block per (b,i) row.
// Single pass over edge per block (QE and A both consume the staged chunk).
// Online softmax (running m,l + rescale). All global reads float4-coalesced:
//   edge: 4 f4/thread/chunk; KT: f4-over-j (1KB/wave); V: f4-over-hc (1KB/wave).
// avred aliases es (es dead after final chunk's phase V/A; avred written in
// epilogue only) -> ~29 KB LDS, 5 blocks/CU.
// ---------------------------------------------------------------------------
__global__ __launch_bounds__(256) void fused_attn(
    const float* __restrict__ edge, const unsigned char* __restrict__ mask,
    const float* __restrict__ We, const float* __restrict__ ws,
    float* __restrict__ out)
{
    __shared__ float qs[256];          // Q row
    __shared__ float Ps[512];          // P[h][d]
    __shared__ float es[4096];         // 64j x 64d edge chunk, swizzled; epilogue: avred
    __shared__ float psum[2 * 8 * 68]; // QK c-half partials [ch][h][j]
    __shared__ float pt[8 * 68];       // scores, then p, [h][j]
    __shared__ float As[512];          // A[h][d]
    __shared__ float mrun[8], lrun[8], fct[8];
    __shared__ int mflag;              // 1 = byte mask, 0 = int32 mask

    const float* Q  = ws + OQ;
    const float* KT = ws + OK;
    const float* V  = ws + OV;
    const float* SK = ws + OS;
    const float* WT = ws + OWT;

    const int t   = threadIdx.x;
    const int row = blockIdx.x;        // b*256 + i
    const int b   = row >> 8;
    const float* erow = edge + (size_t)row * (256 * 64);
    const float scale = 0.17677669529663687f;   // 1/sqrt(32)

    if (t < 8) { mrun[t] = -1e30f; lrun[t] = 0.f; }
    if (t == 0) mflag = 0;
    qs[t] = Q[row * 256 + t];
    __syncthreads();

    {   // mask layout detect: int32 0/1 has zero bytes at off%4!=0
        int found = 0;
        #pragma unroll
        for (int k = 0; k < 16; ++k)
            if ((k & 3) != 0 && mask[t * 16 + k]) found = 1;
        if (found) mflag = 1;          // benign same-value race
    }
    // P[h][d] = sum_c q[h*32+c] * WeT[(h*32+c)*64+d]
    #pragma unroll
    for (int rep = 0; rep < 2; ++rep) {
        int idx = t + rep * 256;
        int h = idx >> 6, d = idx & 63;
        float pa = 0.f, pb = 0.f;
        #pragma unroll
        for (int c = 0; c < 32; c += 2) {
            pa += qs[h * 32 + c]     * WT[(h * 32 + c) * 64 + d];
            pb += qs[h * 32 + c + 1] * WT[(h * 32 + c + 1) * 64 + d];
        }
        Ps[idx] = pa + pb;
    }
    __syncthreads();
    const int MB = mflag;

    float4 accV = make_float4(0.f, 0.f, 0.f, 0.f);  // (hcq = t&63, js = t>>6)
    float accA0 = 0.f, accA1 = 0.f;                 // (h2 = t>>6, d = t&63)

    for (int c4 = 0; c4 < 4; ++c4) {
        const int cb = c4 * 64;

        // ---- phase S: stage edge chunk (swizzled) + QK partials ----
        {
            const float4* src = reinterpret_cast<const float4*>(erow + cb * 64);
            #pragma unroll
            for (int m = 0; m < 4; ++m) {
                int q = m * 256 + t;          // f4 idx 0..1023
                int r = q >> 4, k = q & 15;   // j row, d quad
                *reinterpret_cast<float4*>(&es[r * 64 + ((k ^ (r & 15)) * 4)]) = src[q];
            }
        }
        {   // QK: thread (jq = t&15, h = (t>>4)&7, ch = t>>7); f4 over j
            const int h  = (t >> 4) & 7;
            const int jq = t & 15;
            const int ch = t >> 7;
            const float* kt = KT + b * 65536 + (h * 32 + ch * 16) * 256 + cb + jq * 4;
            const float* qh = qs + h * 32 + ch * 16;
            float4 s4 = make_float4(0.f, 0.f, 0.f, 0.f);
            #pragma unroll
            for (int c = 0; c < 16; ++c) {
                float4 kv = ld4(kt); kt += 256;
                float qv = qh[c];
                s4.x += qv * kv.x; s4.y += qv * kv.y;
                s4.z += qv * kv.z; s4.w += qv * kv.w;
            }
            *reinterpret_cast<float4*>(&psum[(ch * 8 + h) * 68 + jq * 4]) = s4;
        }
        __syncthreads();   // b1

        // ---- phase E: QE from LDS + merge QK halves -> pt scores ----
        {
            const int jl = t & 63, hp = t >> 6;
            const int h0 = 2 * hp, h1 = h0 + 1;
            float qa0 = 0.f, qb0 = 0.f, qa1 = 0.f, qb1 = 0.f;
            #pragma unroll
            for (int k = 0; k < 16; ++k) {
                float4 ev = ld4(&es[jl * 64 + ((k ^ (jl & 15)) * 4)]);
                float4 p0 = ld4(&Ps[h0 * 64 + k * 4]);   // broadcast
                float4 p1 = ld4(&Ps[h1 * 64 + k * 4]);
                qa0 += ev.x * p0.x + ev.y * p0.y; qb0 += ev.z * p0.z + ev.w * p0.w;
                qa1 += ev.x * p1.x + ev.y * p1.y; qb1 += ev.z * p1.z + ev.w * p1.w;
            }
            float s0 = (psum[h0 * 68 + jl] + psum[(8 + h0) * 68 + jl] + qa0 + qb0) * scale;
            float s1 = (psum[h1 * 68 + jl] + psum[(8 + h1) * 68 + jl] + qa1 + qb1) * scale;
            bool mk = MB ? (mask[row * 256 + cb + jl] != 0)
                         : (reinterpret_cast<const int*>(mask)[row * 256 + cb + jl] != 0);
            if (!mk) { s0 = -1e30f; s1 = -1e30f; }
            pt[h0 * 68 + jl] = s0;
            pt[h1 * 68 + jl] = s1;
        }
        __syncthreads();   // b2

        // ---- phase M: chunk max per head, running-max + factor ----
        {
            const int h = t >> 5, l5 = t & 31;
            float m2 = fmaxf(pt[h * 68 + l5], pt[h * 68 + l5 + 32]);
            #pragma unroll
            for (int off = 16; off; off >>= 1) m2 = fmaxf(m2, __shfl_xor(m2, off, 32));
            if (l5 == 0) {
                float mo = mrun[h];
                float mn = fmaxf(mo, m2);
                fct[h] = __expf(mo - mn);   // ==1 when both -1e30 (0-0)
                mrun[h] = mn;
            }
        }
        __syncthreads();   // b3

        // ---- phase P: rescale accs, p = exp(s-m), l update ----
        {
            const float fv = fct[(t & 63) >> 3];
            accV.x *= fv; accV.y *= fv; accV.z *= fv; accV.w *= fv;
            const int h2 = t >> 6;
            accA0 *= fct[h2]; accA1 *= fct[h2 + 4];

            const int jl = t & 63, hp = t >> 6;
            const int h0 = 2 * hp, h1 = h0 + 1;
            float s0 = pt[h0 * 68 + jl], s1 = pt[h1 * 68 + jl];
            float p0 = (s0 > -1e29f) ? __expf(s0 - mrun[h0]) : 0.f;
            float p1 = (s1 > -1e29f) ? __expf(s1 - mrun[h1]) : 0.f;
            pt[h0 * 68 + jl] = p0;
            pt[h1 * 68 + jl] = p1;
            float r0 = p0, r1 = p1;
            #pragma unroll
            for (int off = 32; off; off >>= 1) {
                r0 += __shfl_xor(r0, off);
                r1 += __shfl_xor(r1, off);
            }
            if (jl == 0) {   // one lane per wave; waves own distinct head pairs
                lrun[h0] = lrun[h0] * fct[h0] + r0;
                lrun[h1] = lrun[h1] * fct[h1] + r1;
            }
        }
        __syncthreads();   // b4

        // ---- phase V/A: accumulate AV (global V, f4-coalesced) + A (LDS es) ----
        {
            const int hcq = t & 63, js = t >> 6;
            const int h = hcq >> 3;
            const float* vp = V + ((size_t)(b << 8) + cb + js * 16) * 256 + hcq * 4;
            const float* pr = pt + h * 68 + js * 16;
            #pragma unroll
            for (int jj = 0; jj < 16; ++jj) {
                float4 vv = ld4(vp); vp += 256;       // 1KB/wave coalesced
                float p = pr[jj];                     // 8-addr LDS read
                accV.x += p * vv.x; accV.y += p * vv.y;
                accV.z += p * vv.z; accV.w += p * vv.w;
            }
        }
        {
            const int h2 = t >> 6, d = t & 63;
            const int dq = d >> 2, dl = d & 3;
            const float* pa = pt + h2 * 68;
            const float* pb = pt + (h2 + 4) * 68;
            float a0 = 0.f, a1 = 0.f, b0 = 0.f, b1 = 0.f;
            #pragma unroll 8
            for (int j = 0; j < 64; j += 2) {
                float e0 = es[j * 64 + ((dq ^ (j & 15)) * 4) + dl];
                float e1 = es[(j + 1) * 64 + ((dq ^ ((j + 1) & 15)) * 4) + dl];
                a0 += pa[j] * e0;  a1 += pa[j + 1] * e1;
                b0 += pb[j] * e0;  b1 += pb[j + 1] * e1;
            }
            accA0 += (a0 + a1);
            accA1 += (b0 + b1);
        }
        __syncthreads();   // b5 (es/psum/pt free for next chunk)
    }

    // ---- epilogue: reduce AV partials (avred aliased on es), outE, finish ----
    float* avred = es;   // es dead after final phase V/A (pre-b5); safe alias
    {
        const int hcq = t & 63, js = t >> 6;
        *reinterpret_cast<float4*>(&avred[js * 256 + hcq * 4]) = accV;
        const int h2 = t >> 6, d = t & 63;
        As[h2 * 64 + d]       = accA0;
        As[(h2 + 4) * 64 + d] = accA1;
    }
    __syncthreads();
    {
        float accVf = (avred[t] + avred[256 + t]) + (avred[512 + t] + avred[768 + t]);
        const int h = t >> 5;
        float e0 = 0.f, e1 = 0.f, e2 = 0.f, e3 = 0.f;
        #pragma unroll
        for (int d4 = 0; d4 < 16; ++d4) {
            float4 av = ld4(&As[h * 64 + d4 * 4]);   // broadcast
            e0 += av.x * We[(d4 * 4 + 0) * 256 + t]; // coalesced
            e1 += av.y * We[(d4 * 4 + 1) * 256 + t];
            e2 += av.z * We[(d4 * 4 + 2) * 256 + t];
            e3 += av.w * We[(d4 * 4 + 3) * 256 + t];
        }
        float accE = (e0 + e1) + (e2 + e3);
        float denom = lrun[h];
        float inv = denom > 0.f ? 1.f / denom : 0.f;  // nan_to_num for masked rows
        out[row * 256 + t] = (accVf + accE) * inv + SK[row * 256 + t];
    }
}

// ---------------------------------------------------------------------------
extern "C" void kernel_launch(void* const* d_in, const int* in_sizes, int n_in,
                              void* d_out, int out_size, void* d_ws, size_t ws_size,
                              hipStream_t stream) {
    const float* x    = (const float*)d_in[0];
    const float* edge = (const float*)d_in[1];
    const unsigned char* mask = (const unsigned char*)d_in[2];  // layout auto-detected
    const float* Wq = (const float*)d_in[3];
    const float* bq = (const float*)d_in[4];
    const float* Wk = (const float*)d_in[5];
    const float* bk = (const float*)d_in[6];
    const float* Wv = (const float*)d_in[7];
    const float* bv = (const float*)d_in[8];
    const float* We = (const float*)d_in[9];
    const float* Wsk = (const float*)d_in[10];
    const float* bsk = (const float*)d_in[11];
    float* out = (float*)d_out;
    float* ws  = (float*)d_ws;

    fused_qkvs<<<1025, 256, 0, stream>>>(x, Wq, bq, Wk, bk, Wv, bv, Wsk, bsk, We, ws);
    fused_attn<<<1024, 256, 0, stream>>>(edge, mask, We, ws, out);
}